// Round 1
// baseline (1312.619 us; speedup 1.0000x reference)
//
#include <hip/hip_runtime.h>
#include <hip/hip_bf16.h>

#define VOCAB 100
#define EDIM  128
#define HDIM  256
#define LDIM  64
#define G3    768      // 3*H
#define TT    128
#define BB    4096

typedef float f32x4  __attribute__((ext_vector_type(4)));
typedef short bf16x8 __attribute__((ext_vector_type(8)));

__device__ __forceinline__ short f2bf(float f) {
    unsigned u = __builtin_bit_cast(unsigned, f);
    u += 0x7FFFu + ((u >> 16) & 1u);           // round-to-nearest-even
    return (short)(u >> 16);
}
__device__ __forceinline__ float bf2f(short s) {
    unsigned u = ((unsigned)(unsigned short)s) << 16;
    return __builtin_bit_cast(float, u);
}
__device__ __forceinline__ float sigf(float x)   { return 1.0f / (1.0f + __expf(-x)); }
__device__ __forceinline__ float tanh_f(float x) { return 2.0f / (1.0f + __expf(-2.0f * x)) - 1.0f; }

// ---------------- prep: PT[v][g] = enc_Wih @ embedding[v] + enc_bih ----------------
__global__ void pt_kernel(const float* __restrict__ emb, const float* __restrict__ Wih,
                          const float* __restrict__ bih, float* __restrict__ PT) {
    int v = blockIdx.x;
    __shared__ float se[EDIM];
    for (int e = threadIdx.x; e < EDIM; e += blockDim.x) se[e] = emb[v * EDIM + e];
    __syncthreads();
    for (int g = threadIdx.x; g < G3; g += blockDim.x) {
        const float* wr = Wih + g * EDIM;
        float acc = bih[g];
        #pragma unroll 8
        for (int e = 0; e < EDIM; ++e) acc += se[e] * wr[e];
        PT[v * G3 + g] = acc;
    }
}

// ---------------- LDS layout (bytes) ----------------
#define HP_LD 772                        // f32 cols, +4 pad (bank stagger)
#define H_LD  264                        // bf16 cols, +8 pad (bank stagger)
#define SM_HP   0
#define SM_R2   (16 * HP_LD * 4)                 // 49408
#define SM_HHI  SM_R2                            // enc: short[16][264]
#define SM_HLO  (SM_R2 + 8448)
#define SM_TOK  (SM_R2 + 16896)                  // enc: int[16][128]
#define SM_Z    (SM_R2 + 16896)                  // epilogue: float[16][64] (aliases TOK)
#define SM_HBF  SM_R2                            // dec: short[16][264]
#define SM_OUTW (SM_R2 + 8448)                   // dec: 100 rows * 512B, XOR-swizzled bf16
#define SM_ZP   (SM_R2 + 8448 + 51200)           // dec: float[16][768]
#define SM_TOTAL (SM_R2 + 8448 + 51200 + 49152)  // 158208 B < 160 KiB

__global__ __launch_bounds__(512, 2) void vae_main(
    const int* __restrict__ x, const float* __restrict__ eps,
    const float* __restrict__ PT,
    const float* __restrict__ enc_Whh, const float* __restrict__ enc_bhh,
    const float* __restrict__ mu_W, const float* __restrict__ mu_b,
    const float* __restrict__ lv_W, const float* __restrict__ lv_b,
    const float* __restrict__ di_W, const float* __restrict__ di_b,
    const float* __restrict__ dec_Wih, const float* __restrict__ dec_Whh,
    const float* __restrict__ dec_bih, const float* __restrict__ dec_bhh,
    const float* __restrict__ out_W, const float* __restrict__ out_b,
    float* __restrict__ out)
{
    __shared__ __attribute__((aligned(16))) unsigned char smem[SM_TOTAL];
    float* s_hp  = (float*)(smem + SM_HP);
    short* s_hhi = (short*)(smem + SM_HHI);
    short* s_hlo = (short*)(smem + SM_HLO);
    int*   s_tok = (int*)  (smem + SM_TOK);
    float* s_z   = (float*)(smem + SM_Z);
    short* s_hbf = (short*)(smem + SM_HBF);
    unsigned char* s_outw = smem + SM_OUTW;
    float* s_zp  = (float*)(smem + SM_ZP);

    const int tid  = threadIdx.x;
    const int lane = tid & 63;
    const int wv   = tid >> 6;      // wave 0..7, owns output cols [wv*96, wv*96+96)
    const int l15  = lane & 15;
    const int lgrp = lane >> 4;     // 0..3
    const int bbase = blockIdx.x * 16;
    const int gc  = tid & 255;      // gate thread: fixed h-column
    const int gm2 = tid >> 8;       // 0/1: row parity

    // stage tokens for this batch tile
    for (int i = tid; i < 16 * TT; i += 512) s_tok[i] = x[bbase * TT + i];

    // ---- encoder recurrent weights -> registers (bf16 B-fragments) ----
    bf16x8 Wreg[6][8];
    #pragma unroll
    for (int nt = 0; nt < 6; ++nt) {
        #pragma unroll
        for (int ks = 0; ks < 8; ++ks) {
            const float* p = enc_Whh + (wv * 96 + nt * 16 + l15) * HDIM + ks * 32 + lgrp * 8;
            float4 f0 = *(const float4*)p;
            float4 f1 = *(const float4*)(p + 4);
            bf16x8 w;
            w[0]=f2bf(f0.x); w[1]=f2bf(f0.y); w[2]=f2bf(f0.z); w[3]=f2bf(f0.w);
            w[4]=f2bf(f1.x); w[5]=f2bf(f1.y); w[6]=f2bf(f1.z); w[7]=f2bf(f1.w);
            Wreg[nt][ks] = w;
        }
    }

    float bhr = enc_bhh[gc], bhz = enc_bhh[gc + 256], bhn = enc_bhh[gc + 512];

    const f32x4 z4 = {0.f, 0.f, 0.f, 0.f};
    float hst[8];
    #pragma unroll
    for (int i = 0; i < 8; ++i) hst[i] = 0.0f;
    #pragma unroll
    for (int i = 0; i < 8; ++i) {
        int m = gm2 + 2 * i;
        s_hhi[m * H_LD + gc] = 0;
        s_hlo[m * H_LD + gc] = 0;
    }

    // ===================== ENCODER =====================
    for (int t = 0; t < TT; ++t) {
        __syncthreads();                       // h_hi/h_lo ready
        f32x4 acc[6];
        #pragma unroll
        for (int nt = 0; nt < 6; ++nt) acc[nt] = z4;
        #pragma unroll
        for (int ks = 0; ks < 8; ++ks) {
            const int aoff = l15 * H_LD + ks * 32 + lgrp * 8;
            bf16x8 ahi = *(const bf16x8*)(s_hhi + aoff);
            bf16x8 alo = *(const bf16x8*)(s_hlo + aoff);
            #pragma unroll
            for (int nt = 0; nt < 6; ++nt) {
                acc[nt] = __builtin_amdgcn_mfma_f32_16x16x32_bf16(ahi, Wreg[nt][ks], acc[nt], 0, 0, 0);
                acc[nt] = __builtin_amdgcn_mfma_f32_16x16x32_bf16(alo, Wreg[nt][ks], acc[nt], 0, 0, 0);
            }
        }
        #pragma unroll
        for (int nt = 0; nt < 6; ++nt) {
            int col = wv * 96 + nt * 16 + l15;
            #pragma unroll
            for (int j = 0; j < 4; ++j) s_hp[(lgrp * 4 + j) * HP_LD + col] = acc[nt][j];
        }
        __syncthreads();                       // hp ready
        #pragma unroll
        for (int i = 0; i < 8; ++i) {
            int m = gm2 + 2 * i;
            int tok = s_tok[m * TT + t];
            const float* pt = PT + tok * G3;
            float xr = pt[gc], xz = pt[gc + 256], xn = pt[gc + 512];
            float hr = s_hp[m * HP_LD + gc]       + bhr;
            float hz = s_hp[m * HP_LD + gc + 256] + bhz;
            float hn = s_hp[m * HP_LD + gc + 512] + bhn;
            float r  = sigf(xr + hr), zg = sigf(xz + hz);
            float n  = tanh_f(xn + r * hn);
            float h  = (1.0f - zg) * n + zg * hst[i];
            hst[i] = h;
            short hi = f2bf(h);
            s_hhi[m * H_LD + gc] = hi;
            s_hlo[m * H_LD + gc] = f2bf(h - bf2f(hi));
        }
    }

    // ===================== EPILOGUE: mu / logvar / z / hidden / zp =====================
    __syncthreads();
    #pragma unroll
    for (int i = 0; i < 8; ++i) { int m = gm2 + 2 * i; s_hp[m * HP_LD + gc] = hst[i]; }
    __syncthreads();
    {
        const size_t MU_OFF = (size_t)BB * TT * VOCAB;
        const size_t LV_OFF = MU_OFF + (size_t)BB * LDIM;
        #pragma unroll
        for (int oo = 0; oo < 2; ++oo) {
            int o = tid * 2 + oo;
            int m = o >> 6, j = o & 63;
            const float* mwr = mu_W + j * HDIM;
            const float* lwr = lv_W + j * HDIM;
            float am = mu_b[j], al = lv_b[j];
            #pragma unroll 4
            for (int k = 0; k < HDIM; ++k) { float hv = s_hp[m * HP_LD + k]; am += hv * mwr[k]; al += hv * lwr[k]; }
            size_t bo = (size_t)(bbase + m) * LDIM + j;
            out[MU_OFF + bo] = am;
            out[LV_OFF + bo] = al;
            s_z[m * LDIM + j] = am + eps[bo] * __expf(0.5f * al);
        }
    }
    __syncthreads();
    {
        float ah[8], ar[8], az[8], an[8];
        float dib = di_b[gc];
        float bir = dec_bih[gc], biz = dec_bih[gc + 256], bin_ = dec_bih[gc + 512];
        #pragma unroll
        for (int i = 0; i < 8; ++i) { ah[i] = dib; ar[i] = bir; az[i] = biz; an[i] = bin_; }
        const float* w0 = di_W + gc * LDIM;
        const float* w1 = dec_Wih + gc * LDIM;
        const float* w2 = dec_Wih + (gc + 256) * LDIM;
        const float* w3 = dec_Wih + (gc + 512) * LDIM;
        #pragma unroll 2
        for (int j = 0; j < LDIM; ++j) {
            float a0 = w0[j], a1 = w1[j], a2 = w2[j], a3 = w3[j];
            #pragma unroll
            for (int i = 0; i < 8; ++i) {
                float zv = s_z[(gm2 + 2 * i) * LDIM + j];
                ah[i] += zv * a0; ar[i] += zv * a1; az[i] += zv * a2; an[i] += zv * a3;
            }
        }
        #pragma unroll
        for (int i = 0; i < 8; ++i) {
            int m = gm2 + 2 * i;
            float th = tanh_f(ah[i]);
            hst[i] = th;
            s_zp[m * G3 + gc]       = ar[i];
            s_zp[m * G3 + gc + 256] = az[i];
            s_zp[m * G3 + gc + 512] = an[i];
            s_hbf[m * H_LD + gc] = f2bf(th);
        }
    }
    __syncthreads();                       // s_z dead; safe to overwrite with out_W
    // stage out_W -> LDS bf16, XOR-swizzled (bank-conflict-free B-frag reads)
    for (int idx = tid; idx < VOCAB * HDIM; idx += 512) {
        int r = idx >> 8, k = idx & 255;
        *(short*)(s_outw + r * 512 + ((2 * k) ^ ((r & 7) << 4))) = f2bf(out_W[idx]);
    }
    // decoder recurrent weights -> registers
    #pragma unroll
    for (int nt = 0; nt < 6; ++nt) {
        #pragma unroll
        for (int ks = 0; ks < 8; ++ks) {
            const float* p = dec_Whh + (wv * 96 + nt * 16 + l15) * HDIM + ks * 32 + lgrp * 8;
            float4 f0 = *(const float4*)p;
            float4 f1 = *(const float4*)(p + 4);
            bf16x8 w;
            w[0]=f2bf(f0.x); w[1]=f2bf(f0.y); w[2]=f2bf(f0.z); w[3]=f2bf(f0.w);
            w[4]=f2bf(f1.x); w[5]=f2bf(f1.y); w[6]=f2bf(f1.z); w[7]=f2bf(f1.w);
            Wreg[nt][ks] = w;
        }
    }
    bhr = dec_bhh[gc]; bhz = dec_bhh[gc + 256]; bhn = dec_bhh[gc + 512];
    const int vcol = wv * 16 + l15;
    const int orow = (vcol < VOCAB) ? vcol : (VOCAB - 1);
    float ob = 0.0f;
    if (wv < 7 && vcol < VOCAB) ob = out_b[vcol];

    // ===================== DECODER (vocab projection fused) =====================
    for (int t = 0; t < TT; ++t) {
        __syncthreads();                       // h_bf (= h_t) ready
        f32x4 acc[6];
        #pragma unroll
        for (int nt = 0; nt < 6; ++nt) acc[nt] = z4;
        f32x4 aco = z4;
        const bool doOut = (t > 0) && (wv < 7);
        #pragma unroll
        for (int ks = 0; ks < 8; ++ks) {
            bf16x8 a = *(const bf16x8*)(s_hbf + l15 * H_LD + ks * 32 + lgrp * 8);
            #pragma unroll
            for (int nt = 0; nt < 6; ++nt)
                acc[nt] = __builtin_amdgcn_mfma_f32_16x16x32_bf16(a, Wreg[nt][ks], acc[nt], 0, 0, 0);
            if (doOut) {
                bf16x8 wo = *(const bf16x8*)(s_outw + orow * 512 + ((ks * 64 + lgrp * 16) ^ ((orow & 7) << 4)));
                aco = __builtin_amdgcn_mfma_f32_16x16x32_bf16(a, wo, aco, 0, 0, 0);
            }
        }
        if (doOut && vcol < VOCAB) {           // logits[:, t-1, :] from h_t
            size_t base = (size_t)(bbase + lgrp * 4) * (TT * VOCAB) + (size_t)(t - 1) * VOCAB + vcol;
            #pragma unroll
            for (int j = 0; j < 4; ++j) out[base + (size_t)j * (TT * VOCAB)] = aco[j] + ob;
        }
        #pragma unroll
        for (int nt = 0; nt < 6; ++nt) {
            int col = wv * 96 + nt * 16 + l15;
            #pragma unroll
            for (int j = 0; j < 4; ++j) s_hp[(lgrp * 4 + j) * HP_LD + col] = acc[nt][j];
        }
        __syncthreads();                       // hp ready
        #pragma unroll
        for (int i = 0; i < 8; ++i) {
            int m = gm2 + 2 * i;
            float xr = s_zp[m * G3 + gc], xz = s_zp[m * G3 + gc + 256], xn = s_zp[m * G3 + gc + 512];
            float hr = s_hp[m * HP_LD + gc]       + bhr;
            float hz = s_hp[m * HP_LD + gc + 256] + bhz;
            float hn = s_hp[m * HP_LD + gc + 512] + bhn;
            float r  = sigf(xr + hr), zg = sigf(xz + hz);
            float n  = tanh_f(xn + r * hn);
            float h  = (1.0f - zg) * n + zg * hst[i];
            hst[i] = h;
            s_hbf[m * H_LD + gc] = f2bf(h);
        }
    }
    // final vocab projection: logits[:, 127, :] from h_128
    __syncthreads();
    if (wv < 7) {
        f32x4 aco = z4;
        #pragma unroll
        for (int ks = 0; ks < 8; ++ks) {
            bf16x8 a  = *(const bf16x8*)(s_hbf + l15 * H_LD + ks * 32 + lgrp * 8);
            bf16x8 wo = *(const bf16x8*)(s_outw + orow * 512 + ((ks * 64 + lgrp * 16) ^ ((orow & 7) << 4)));
            aco = __builtin_amdgcn_mfma_f32_16x16x32_bf16(a, wo, aco, 0, 0, 0);
        }
        if (vcol < VOCAB) {
            size_t base = (size_t)(bbase + lgrp * 4) * (TT * VOCAB) + (size_t)(TT - 1) * VOCAB + vcol;
            #pragma unroll
            for (int j = 0; j < 4; ++j) out[base + (size_t)j * (TT * VOCAB)] = aco[j] + ob;
        }
    }
}

extern "C" void kernel_launch(void* const* d_in, const int* in_sizes, int n_in,
                              void* d_out, int out_size, void* d_ws, size_t ws_size,
                              hipStream_t stream) {
    const int*   x       = (const int*)  d_in[0];
    const float* eps     = (const float*)d_in[1];
    const float* emb     = (const float*)d_in[2];
    const float* enc_Wih = (const float*)d_in[3];
    const float* enc_Whh = (const float*)d_in[4];
    const float* enc_bih = (const float*)d_in[5];
    const float* enc_bhh = (const float*)d_in[6];
    const float* mu_W    = (const float*)d_in[7];
    const float* mu_b    = (const float*)d_in[8];
    const float* lv_W    = (const float*)d_in[9];
    const float* lv_b    = (const float*)d_in[10];
    const float* di_W    = (const float*)d_in[11];
    const float* di_b    = (const float*)d_in[12];
    const float* dec_Wih = (const float*)d_in[13];
    const float* dec_Whh = (const float*)d_in[14];
    const float* dec_bih = (const float*)d_in[15];
    const float* dec_bhh = (const float*)d_in[16];
    const float* out_W   = (const float*)d_in[17];
    const float* out_b   = (const float*)d_in[18];
    float* out = (float*)d_out;
    float* PT  = (float*)d_ws;   // [100][768] f32 = 307200 B

    pt_kernel<<<VOCAB, 256, 0, stream>>>(emb, enc_Wih, enc_bih, PT);
    vae_main<<<BB / 16, 512, 0, stream>>>(x, eps, PT, enc_Whh, enc_bhh,
        mu_W, mu_b, lv_W, lv_b, di_W, di_b, dec_Wih, dec_Whh, dec_bih, dec_bhh,
        out_W, out_b, out);
}